// Round 10
// baseline (59.530 us; speedup 1.0000x reference)
//
#include <hip/hip_runtime.h>
#include <math.h>

#define N 8192
#define F 128
#define U 128
#define CAP 128          // max stored neighbors per row (~33 expected, 16-sigma safe)
#define GEMM_BLOCKS 256  // blocks 0..255 do y = x@W first, then scan their rows
#define FCHUNK 32        // W staged in 4 chunks of 32 f-rows (16 KB LDS)
#define GRID_BLKS 2048   // exact co-residency: 256 CU x 8 blocks (16KB LDS, 32 waves)

typedef float f32x4 __attribute__((ext_vector_type(4)));
typedef unsigned short u16;
typedef unsigned int u32;
typedef unsigned long long u64;

__device__ __forceinline__ u16 f2bf(float f) {        // fp32 -> bf16 RNE
    u32 u = __float_as_uint(f);
    return (u16)((u + 0x7fffu + ((u >> 16) & 1u)) >> 16);
}
__device__ __forceinline__ float bflo(u32 v) { return __uint_as_float(v << 16); }
__device__ __forceinline__ float bfhi(u32 v) { return __uint_as_float(v & 0xffff0000u); }

// ---------------------------------------------------------------------------
// Fused kernel: 2048 blocks = 8192 waves = exactly ONE adjacency row per wave.
//   blocks 0..255 : y = x@W (W in 4 x 16KB LDS chunks) first, then scan.
// Scan: branch-free bitmap (adj in {0,1} -> IEEE bit 23), NONTEMPORAL loads
// (read-once 256MB must not allocate in L2/IC), and an explicit 4-deep
// DOUBLE-BUFFER so the wave's VMEM queue never drains while bitmap VALU runs
// (R9's VGPR=36 shows a single 8-batch in regs -> vmcnt(0) bubble per batch).
// Epilogue per row: popcll + shfl prefix scan + ffsll walk -> u16 col list.
// ---------------------------------------------------------------------------
__global__ __launch_bounds__(256) void k_fused(const float* __restrict__ adj,
                                               const float* __restrict__ x,
                                               const float* __restrict__ W,
                                               float* __restrict__ dinv,
                                               int* __restrict__ cnt,
                                               u16* __restrict__ cols,
                                               u16* __restrict__ y) {
    __shared__ float sW[FCHUNK * U];     // 16 KB (GEMM branch only)
    const int tid = threadIdx.x;

    if (blockIdx.x < GEMM_BLOCKS) {
        // ---------------- GEMM: y = x @ W ----------------
        const int l  = tid & 31;            // unit group: u0 = l*4
        const int p  = tid >> 5;            // node group: 4 nodes each
        const int n0 = blockIdx.x * 32 + p * 4;
        const float* xr = x + (size_t)n0 * F;

        float acc[4][4];
        #pragma unroll
        for (int i = 0; i < 4; ++i)
            #pragma unroll
            for (int u = 0; u < 4; ++u) acc[i][u] = 0.f;

        for (int chunk = 0; chunk < F / FCHUNK; ++chunk) {
            {   // stage 32 f-rows of W (16 KB, 4 float4/thread)
                const float4* Wp = (const float4*)(W + (size_t)chunk * FCHUNK * U);
                float4* sWp = (float4*)sW;
                #pragma unroll
                for (int k = 0; k < (FCHUNK * U / 4) / 256; ++k)   // 4 iters
                    sWp[tid + k * 256] = Wp[tid + k * 256];
            }
            __syncthreads();

            const int fb = chunk * FCHUNK;
            #pragma unroll
            for (int f = 0; f < FCHUNK; f += 4) {
                f32x4 xa = *(const f32x4*)(xr + 0 * F + fb + f);
                f32x4 xb = *(const f32x4*)(xr + 1 * F + fb + f);
                f32x4 xc = *(const f32x4*)(xr + 2 * F + fb + f);
                f32x4 xd = *(const f32x4*)(xr + 3 * F + fb + f);
                #pragma unroll
                for (int k = 0; k < 4; ++k) {
                    const f32x4 w = *(const f32x4*)(sW + (f + k) * U + l * 4);
                    #pragma unroll
                    for (int u = 0; u < 4; ++u) {
                        acc[0][u] = fmaf(xa[k], w[u], acc[0][u]);
                        acc[1][u] = fmaf(xb[k], w[u], acc[1][u]);
                        acc[2][u] = fmaf(xc[k], w[u], acc[2][u]);
                        acc[3][u] = fmaf(xd[k], w[u], acc[3][u]);
                    }
                }
            }
            __syncthreads();   // protect sW before next chunk's overwrite
        }

        #pragma unroll
        for (int i = 0; i < 4; ++i) {
            ushort4 o;
            o.x = f2bf(acc[i][0]);
            o.y = f2bf(acc[i][1]);
            o.z = f2bf(acc[i][2]);
            o.w = f2bf(acc[i][3]);
            *(ushort4*)(y + (size_t)(n0 + i) * U + l * 4) = o;
        }
    }

    // ---------------- row scan: one row per wave, branch-free, dbuf ----------
    const int wid  = tid >> 6;
    const int lane = tid & 63;
    const int row  = blockIdx.x * 4 + wid;     // 2048*4 == N exactly

    const f32x4* rp = (const f32x4*)(adj + (size_t)row * N);
    u16* crow = cols + (size_t)row * CAP;

    // per-lane 128-bit nonzero bitmap: group g (my g-th float4), bit (g&7)*4+comp
    u32 bm[4] = {0u, 0u, 0u, 0u};

    f32x4 va[4], vb[4];
    #pragma unroll
    for (int t = 0; t < 4; ++t)                 // prologue: batch 0 -> va
        va[t] = __builtin_nontemporal_load(&rp[t * 64 + lane]);

    #pragma unroll
    for (int kb = 0; kb < 8; ++kb) {            // 8 batches of 4 (fully unrolled)
        // issue NEXT batch into the other buffer before touching this one
        if (kb < 7) {
            #pragma unroll
            for (int t = 0; t < 4; ++t) {
                const f32x4 nv = __builtin_nontemporal_load(&rp[((kb + 1) * 4 + t) * 64 + lane]);
                if (kb & 1) va[t] = nv; else vb[t] = nv;   // static after unroll
            }
        }
        #pragma unroll
        for (int t = 0; t < 4; ++t) {
            const f32x4 v = (kb & 1) ? vb[t] : va[t];      // static after unroll
            const int g = kb * 4 + t;
            // adj values are exactly 0.0f or 1.0f: bit 23 of the encoding.
            const u32 b0 = (__float_as_uint(v[0]) >> 23) & 1u;
            const u32 b1 = (__float_as_uint(v[1]) >> 22) & 2u;
            const u32 b2 = (__float_as_uint(v[2]) >> 21) & 4u;
            const u32 b3 = (__float_as_uint(v[3]) >> 20) & 8u;
            bm[g >> 3] |= (b0 | b1 | b2 | b3) << ((g & 7) * 4);
        }
    }

    // counts + exclusive prefix across lanes (order within row is irrelevant)
    const u64 lo = ((u64)bm[1] << 32) | bm[0];   // groups 0..15
    const u64 hi = ((u64)bm[3] << 32) | bm[2];   // groups 16..31
    const int mycnt = __popcll(lo) + __popcll(hi);

    int inc = mycnt;
    #pragma unroll
    for (int off = 1; off < 64; off <<= 1) {
        const int t = __shfl_up(inc, off);
        if (lane >= off) inc += t;
    }
    const int total = __shfl(inc, 63);           // row sum (== nnz, binary adj)
    int pos = inc - mycnt;                       // exclusive prefix

    // extract this lane's set bits (~0.5 avg) -> compacted u16 cols
    u64 b = lo;
    int gbase = 0;
    #pragma unroll
    for (int h = 0; h < 2; ++h) {
        while (b) {
            const int p = __ffsll((unsigned long long)b) - 1;
            b &= b - 1;
            const int g   = gbase + (p >> 2);            // which of my float4s
            const int col = g * 256 + lane * 4 + (p & 3);
            if (pos < CAP) crow[pos] = (u16)col;
            ++pos;
        }
        b = hi;
        gbase = 16;
    }

    if (lane == 0) {
        dinv[row] = 1.0f / sqrtf((float)total + 1.0f);   // +1: self-loop from A+I
        cnt[row]  = min(total, CAP);
    }
}

// ---------------------------------------------------------------------------
// Kernel 2: out[i] = relu(d_i*(d_i*y[i] + sum_j d_j*y[j]) + b).
// One wave per node, zero LDS, full occupancy. 8-neighbor batches:
// 1 uint4 load = 8 packed u16 indices -> 8 parallel dinv gathers ->
// 8 parallel y-row gathers (bf16x2/lane). Bias + ReLU fused at the store.
// ---------------------------------------------------------------------------
__global__ __launch_bounds__(256, 4) void k_agg(const u16* __restrict__ y,
                                                const float* __restrict__ bias,
                                                const float* __restrict__ dinv,
                                                const int* __restrict__ cnt,
                                                const u16* __restrict__ cols,
                                                float* __restrict__ out) {
    const int wid  = threadIdx.x >> 6;
    const int lane = threadIdx.x & 63;
    const int node = blockIdx.x * 4 + wid;

    const int   c  = cnt[node];
    const float di = dinv[node];
    const u16* crow = cols + (size_t)node * CAP;

    const u32 self = *(const u32*)(y + (size_t)node * F + lane * 2);
    float acc0 = di * bflo(self);
    float acc1 = di * bfhi(self);

    for (int m0 = 0; m0 < c; m0 += 8) {
        const uint4 cw = *(const uint4*)(crow + m0);   // 8 u16 indices, 16B aligned
        const u32 cwa[4] = {cw.x, cw.y, cw.z, cw.w};
        int   jj[8];
        float dj[8];
        #pragma unroll
        for (int k = 0; k < 8; ++k) {
            const int  jraw  = (int)((cwa[k >> 1] >> ((k & 1) * 16)) & 0xffffu);
            const bool valid = (m0 + k) < c;
            jj[k] = valid ? jraw : node;               // safe pad address
            dj[k] = valid ? dinv[jj[k]] : 0.f;         // weight 0 kills pad term
        }
        #pragma unroll
        for (int k = 0; k < 8; ++k) {
            const u32 v = *(const u32*)(y + (size_t)jj[k] * F + lane * 2);
            acc0 = fmaf(dj[k], bflo(v), acc0);
            acc1 = fmaf(dj[k], bfhi(v), acc1);
        }
    }

    const float2 bb = *(const float2*)(bias + lane * 2);
    const float o0 = fmaxf(fmaf(di, acc0, bb.x), 0.f);
    const float o1 = fmaxf(fmaf(di, acc1, bb.y), 0.f);
    *(float2*)(out + (size_t)node * F + lane * 2) = make_float2(o0, o1);
}

extern "C" void kernel_launch(void* const* d_in, const int* in_sizes, int n_in,
                              void* d_out, int out_size, void* d_ws, size_t ws_size,
                              hipStream_t stream) {
    const float* x   = (const float*)d_in[0];   // [N, F]
    const float* adj = (const float*)d_in[1];   // [N, N]
    const float* W   = (const float*)d_in[2];   // [F, U]
    const float* b   = (const float*)d_in[3];   // [U]
    float* out = (float*)d_out;                 // [N, U]

    // workspace: dinv f32[N] 32KB | cnt i32[N] 32KB | cols u16[N*CAP] 2MB |
    //            y bf16[N*U] 2MB -> ~4.26MB
    float* dinv = (float*)d_ws;
    int*   cnt  = (int*)((char*)d_ws + (size_t)N * 4);
    u16*   cols = (u16*)((char*)d_ws + (size_t)N * 8);
    u16*   yy   = (u16*)((char*)d_ws + (size_t)N * 8 + (size_t)N * CAP * 2);

    k_fused<<<GRID_BLKS, 256, 0, stream>>>(adj, x, W, dinv, cnt, cols, yy);
    k_agg  <<<N / 4,     256, 0, stream>>>(yy, b, dinv, cnt, cols, out);
}

// Round 11
// 58.985 us; speedup vs baseline: 1.0092x; 1.0092x over previous
//
#include <hip/hip_runtime.h>
#include <math.h>

#define N 8192
#define F 128
#define U 128
#define CAP 128          // max stored neighbors per row (~33 expected, 16-sigma safe)
#define GEMM_BLOCKS 256  // blocks 0..255 do y = x@W first, then scan their rows
#define FCHUNK 32        // W staged in 4 chunks of 32 f-rows (16 KB LDS)
#define GRID_BLKS 1024   // 4096 waves x 2 consecutive rows = 8192 rows
#define ROWS_PER_WAVE 2  // 64KB sequential stream per wave (4096 streams, was 8192)

typedef float f32x4 __attribute__((ext_vector_type(4)));
typedef unsigned short u16;
typedef unsigned int u32;
typedef unsigned long long u64;

__device__ __forceinline__ u16 f2bf(float f) {        // fp32 -> bf16 RNE
    u32 u = __float_as_uint(f);
    return (u16)((u + 0x7fffu + ((u >> 16) & 1u)) >> 16);
}
__device__ __forceinline__ float bflo(u32 v) { return __uint_as_float(v << 16); }
__device__ __forceinline__ float bfhi(u32 v) { return __uint_as_float(v & 0xffff0000u); }

// ---------------------------------------------------------------------------
// Fused kernel: 1024 blocks = 4096 waves; each wave scans TWO consecutive
// adjacency rows (64KB sequential address range) — halves the concurrent
// stream count vs R9 (DRAM page-locality probe; the only unfalsified theory
// for the 5.4 vs 6.3 TB/s read gap).
//   blocks 0..255 : y = x@W (W in 4 x 16KB LDS chunks) first, then scan.
// Scan per row: branch-free bitmap (adj in {0,1} -> IEEE bit 23); hot loop is
// pure loads + shift/or (R9 structure: no NT, no dbuf — both tested, both
// regressed). Epilogue: popcll + shfl prefix scan + ffsll walk -> u16 cols.
// ---------------------------------------------------------------------------
__global__ __launch_bounds__(256) void k_fused(const float* __restrict__ adj,
                                               const float* __restrict__ x,
                                               const float* __restrict__ W,
                                               float* __restrict__ dinv,
                                               int* __restrict__ cnt,
                                               u16* __restrict__ cols,
                                               u16* __restrict__ y) {
    __shared__ float sW[FCHUNK * U];     // 16 KB (GEMM branch only)
    const int tid = threadIdx.x;

    if (blockIdx.x < GEMM_BLOCKS) {
        // ---------------- GEMM: y = x @ W ----------------
        const int l  = tid & 31;            // unit group: u0 = l*4
        const int p  = tid >> 5;            // node group: 4 nodes each
        const int n0 = blockIdx.x * 32 + p * 4;
        const float* xr = x + (size_t)n0 * F;

        float acc[4][4];
        #pragma unroll
        for (int i = 0; i < 4; ++i)
            #pragma unroll
            for (int u = 0; u < 4; ++u) acc[i][u] = 0.f;

        for (int chunk = 0; chunk < F / FCHUNK; ++chunk) {
            {   // stage 32 f-rows of W (16 KB, 4 float4/thread)
                const float4* Wp = (const float4*)(W + (size_t)chunk * FCHUNK * U);
                float4* sWp = (float4*)sW;
                #pragma unroll
                for (int k = 0; k < (FCHUNK * U / 4) / 256; ++k)   // 4 iters
                    sWp[tid + k * 256] = Wp[tid + k * 256];
            }
            __syncthreads();

            const int fb = chunk * FCHUNK;
            #pragma unroll
            for (int f = 0; f < FCHUNK; f += 4) {
                f32x4 xa = *(const f32x4*)(xr + 0 * F + fb + f);
                f32x4 xb = *(const f32x4*)(xr + 1 * F + fb + f);
                f32x4 xc = *(const f32x4*)(xr + 2 * F + fb + f);
                f32x4 xd = *(const f32x4*)(xr + 3 * F + fb + f);
                #pragma unroll
                for (int k = 0; k < 4; ++k) {
                    const f32x4 w = *(const f32x4*)(sW + (f + k) * U + l * 4);
                    #pragma unroll
                    for (int u = 0; u < 4; ++u) {
                        acc[0][u] = fmaf(xa[k], w[u], acc[0][u]);
                        acc[1][u] = fmaf(xb[k], w[u], acc[1][u]);
                        acc[2][u] = fmaf(xc[k], w[u], acc[2][u]);
                        acc[3][u] = fmaf(xd[k], w[u], acc[3][u]);
                    }
                }
            }
            __syncthreads();   // protect sW before next chunk's overwrite
        }

        #pragma unroll
        for (int i = 0; i < 4; ++i) {
            ushort4 o;
            o.x = f2bf(acc[i][0]);
            o.y = f2bf(acc[i][1]);
            o.z = f2bf(acc[i][2]);
            o.w = f2bf(acc[i][3]);
            *(ushort4*)(y + (size_t)(n0 + i) * U + l * 4) = o;
        }
    }

    // ------- row scan: 2 consecutive rows per wave, branch-free bitmap -------
    const int wid  = tid >> 6;
    const int lane = tid & 63;
    const int wgid = blockIdx.x * 4 + wid;       // 0..4095

    for (int rr = 0; rr < ROWS_PER_WAVE; ++rr) {
        const int row = wgid * ROWS_PER_WAVE + rr;   // contiguous 64KB per wave

        const f32x4* rp = (const f32x4*)(adj + (size_t)row * N);
        u16* crow = cols + (size_t)row * CAP;

        // per-lane 128-bit bitmap: group g (my g-th float4), bit (g&7)*4+comp
        u32 bm[4] = {0u, 0u, 0u, 0u};

        #pragma unroll
        for (int kb = 0; kb < 4; ++kb) {           // 4 batches of 8 loads
            f32x4 v[8];
            #pragma unroll
            for (int t = 0; t < 8; ++t)            // 8 loads, nothing between
                v[t] = rp[(kb * 8 + t) * 64 + lane];

            #pragma unroll
            for (int t = 0; t < 8; ++t) {
                const int g = kb * 8 + t;
                // adj values are exactly 0.0f or 1.0f: bit 23 of the encoding.
                const u32 b0 = (__float_as_uint(v[t][0]) >> 23) & 1u;
                const u32 b1 = (__float_as_uint(v[t][1]) >> 22) & 2u;
                const u32 b2 = (__float_as_uint(v[t][2]) >> 21) & 4u;
                const u32 b3 = (__float_as_uint(v[t][3]) >> 20) & 8u;
                bm[g >> 3] |= (b0 | b1 | b2 | b3) << ((g & 7) * 4);
            }
        }

        // counts + exclusive prefix across lanes (order within row irrelevant)
        const u64 lo = ((u64)bm[1] << 32) | bm[0];   // groups 0..15
        const u64 hi = ((u64)bm[3] << 32) | bm[2];   // groups 16..31
        const int mycnt = __popcll(lo) + __popcll(hi);

        int inc = mycnt;
        #pragma unroll
        for (int off = 1; off < 64; off <<= 1) {
            const int t = __shfl_up(inc, off);
            if (lane >= off) inc += t;
        }
        const int total = __shfl(inc, 63);           // row sum (binary adj)
        int pos = inc - mycnt;                       // exclusive prefix

        // extract this lane's set bits (~0.5 avg) -> compacted u16 cols
        u64 b = lo;
        int gbase = 0;
        #pragma unroll
        for (int h = 0; h < 2; ++h) {
            while (b) {
                const int p = __ffsll((unsigned long long)b) - 1;
                b &= b - 1;
                const int g   = gbase + (p >> 2);            // which float4
                const int col = g * 256 + lane * 4 + (p & 3);
                if (pos < CAP) crow[pos] = (u16)col;
                ++pos;
            }
            b = hi;
            gbase = 16;
        }

        if (lane == 0) {
            dinv[row] = 1.0f / sqrtf((float)total + 1.0f);   // +1: self-loop
            cnt[row]  = min(total, CAP);
        }
    }
}

// ---------------------------------------------------------------------------
// Kernel 2: out[i] = relu(d_i*(d_i*y[i] + sum_j d_j*y[j]) + b).
// One wave per node, zero LDS, full occupancy. 8-neighbor batches:
// 1 uint4 load = 8 packed u16 indices -> 8 parallel dinv gathers ->
// 8 parallel y-row gathers (bf16x2/lane). Bias + ReLU fused at the store.
// ---------------------------------------------------------------------------
__global__ __launch_bounds__(256, 4) void k_agg(const u16* __restrict__ y,
                                                const float* __restrict__ bias,
                                                const float* __restrict__ dinv,
                                                const int* __restrict__ cnt,
                                                const u16* __restrict__ cols,
                                                float* __restrict__ out) {
    const int wid  = threadIdx.x >> 6;
    const int lane = threadIdx.x & 63;
    const int node = blockIdx.x * 4 + wid;

    const int   c  = cnt[node];
    const float di = dinv[node];
    const u16* crow = cols + (size_t)node * CAP;

    const u32 self = *(const u32*)(y + (size_t)node * F + lane * 2);
    float acc0 = di * bflo(self);
    float acc1 = di * bfhi(self);

    for (int m0 = 0; m0 < c; m0 += 8) {
        const uint4 cw = *(const uint4*)(crow + m0);   // 8 u16 indices, 16B aligned
        const u32 cwa[4] = {cw.x, cw.y, cw.z, cw.w};
        int   jj[8];
        float dj[8];
        #pragma unroll
        for (int k = 0; k < 8; ++k) {
            const int  jraw  = (int)((cwa[k >> 1] >> ((k & 1) * 16)) & 0xffffu);
            const bool valid = (m0 + k) < c;
            jj[k] = valid ? jraw : node;               // safe pad address
            dj[k] = valid ? dinv[jj[k]] : 0.f;         // weight 0 kills pad term
        }
        #pragma unroll
        for (int k = 0; k < 8; ++k) {
            const u32 v = *(const u32*)(y + (size_t)jj[k] * F + lane * 2);
            acc0 = fmaf(dj[k], bflo(v), acc0);
            acc1 = fmaf(dj[k], bfhi(v), acc1);
        }
    }

    const float2 bb = *(const float2*)(bias + lane * 2);
    const float o0 = fmaxf(fmaf(di, acc0, bb.x), 0.f);
    const float o1 = fmaxf(fmaf(di, acc1, bb.y), 0.f);
    *(float2*)(out + (size_t)node * F + lane * 2) = make_float2(o0, o1);
}

extern "C" void kernel_launch(void* const* d_in, const int* in_sizes, int n_in,
                              void* d_out, int out_size, void* d_ws, size_t ws_size,
                              hipStream_t stream) {
    const float* x   = (const float*)d_in[0];   // [N, F]
    const float* adj = (const float*)d_in[1];   // [N, N]
    const float* W   = (const float*)d_in[2];   // [F, U]
    const float* b   = (const float*)d_in[3];   // [U]
    float* out = (float*)d_out;                 // [N, U]

    // workspace: dinv f32[N] 32KB | cnt i32[N] 32KB | cols u16[N*CAP] 2MB |
    //            y bf16[N*U] 2MB -> ~4.26MB
    float* dinv = (float*)d_ws;
    int*   cnt  = (int*)((char*)d_ws + (size_t)N * 4);
    u16*   cols = (u16*)((char*)d_ws + (size_t)N * 8);
    u16*   yy   = (u16*)((char*)d_ws + (size_t)N * 8 + (size_t)N * CAP * 2);

    k_fused<<<GRID_BLKS, 256, 0, stream>>>(adj, x, W, dinv, cnt, cols, yy);
    k_agg  <<<N / 4,     256, 0, stream>>>(yy, b, dinv, cnt, cols, out);
}

// Round 12
// 56.339 us; speedup vs baseline: 1.0566x; 1.0470x over previous
//
#include <hip/hip_runtime.h>
#include <math.h>

#define N 8192
#define F 128
#define U 128
#define CAP 128          // max stored neighbors per row (~33 expected, 16-sigma safe)
#define GEMM_BLOCKS 256  // blocks 0..255 do y = x@W first, then scan their rows
#define FCHUNK 32        // W staged in 4 chunks of 32 f-rows (16 KB LDS)
#define GRID_BLKS 2048   // exact co-residency: 256 CU x 8 blocks (16KB LDS, 32 waves)

typedef float f32x4 __attribute__((ext_vector_type(4)));
typedef unsigned short u16;
typedef unsigned int u32;
typedef unsigned long long u64;

__device__ __forceinline__ u16 f2bf(float f) {        // fp32 -> bf16 RNE
    u32 u = __float_as_uint(f);
    return (u16)((u + 0x7fffu + ((u >> 16) & 1u)) >> 16);
}
__device__ __forceinline__ float bflo(u32 v) { return __uint_as_float(v << 16); }
__device__ __forceinline__ float bfhi(u32 v) { return __uint_as_float(v & 0xffff0000u); }

// ---------------------------------------------------------------------------
// Fused kernel: 2048 blocks = 8192 waves = exactly ONE adjacency row per wave.
//   blocks 0..255 : y = x@W (W in 4 x 16KB LDS chunks) first, then scan.
// Scan is BRANCH-FREE: adj is exactly {0.0f,1.0f}, so nonzero-ness is IEEE
// bit 23. Hot loop = loads + shift/or into a per-lane 128-bit bitmap; no
// ballots, no branches, no stores. (Probed and rejected: NT loads (R10 -3us),
// explicit dbuf (R10), 2 rows/wave (R11), dynamic row claim (R7 -167us!),
// ballot-compaction in hot loop (R8).)
// Epilogue per row: 2 popcll + 6-step shfl prefix scan + per-lane ffsll walk
// (~0.5 set bits/lane) writes the compacted u16 column list.
// ---------------------------------------------------------------------------
__global__ __launch_bounds__(256) void k_fused(const float* __restrict__ adj,
                                               const float* __restrict__ x,
                                               const float* __restrict__ W,
                                               float* __restrict__ dinv,
                                               int* __restrict__ cnt,
                                               u16* __restrict__ cols,
                                               u16* __restrict__ y) {
    __shared__ float sW[FCHUNK * U];     // 16 KB (GEMM branch only)
    const int tid = threadIdx.x;

    if (blockIdx.x < GEMM_BLOCKS) {
        // ---------------- GEMM: y = x @ W ----------------
        const int l  = tid & 31;            // unit group: u0 = l*4
        const int p  = tid >> 5;            // node group: 4 nodes each
        const int n0 = blockIdx.x * 32 + p * 4;
        const float* xr = x + (size_t)n0 * F;

        float acc[4][4];
        #pragma unroll
        for (int i = 0; i < 4; ++i)
            #pragma unroll
            for (int u = 0; u < 4; ++u) acc[i][u] = 0.f;

        for (int chunk = 0; chunk < F / FCHUNK; ++chunk) {
            {   // stage 32 f-rows of W (16 KB, 4 float4/thread)
                const float4* Wp = (const float4*)(W + (size_t)chunk * FCHUNK * U);
                float4* sWp = (float4*)sW;
                #pragma unroll
                for (int k = 0; k < (FCHUNK * U / 4) / 256; ++k)   // 4 iters
                    sWp[tid + k * 256] = Wp[tid + k * 256];
            }
            __syncthreads();

            const int fb = chunk * FCHUNK;
            #pragma unroll
            for (int f = 0; f < FCHUNK; f += 4) {
                f32x4 xa = *(const f32x4*)(xr + 0 * F + fb + f);
                f32x4 xb = *(const f32x4*)(xr + 1 * F + fb + f);
                f32x4 xc = *(const f32x4*)(xr + 2 * F + fb + f);
                f32x4 xd = *(const f32x4*)(xr + 3 * F + fb + f);
                #pragma unroll
                for (int k = 0; k < 4; ++k) {
                    const f32x4 w = *(const f32x4*)(sW + (f + k) * U + l * 4);
                    #pragma unroll
                    for (int u = 0; u < 4; ++u) {
                        acc[0][u] = fmaf(xa[k], w[u], acc[0][u]);
                        acc[1][u] = fmaf(xb[k], w[u], acc[1][u]);
                        acc[2][u] = fmaf(xc[k], w[u], acc[2][u]);
                        acc[3][u] = fmaf(xd[k], w[u], acc[3][u]);
                    }
                }
            }
            __syncthreads();   // protect sW before next chunk's overwrite
        }

        #pragma unroll
        for (int i = 0; i < 4; ++i) {
            ushort4 o;
            o.x = f2bf(acc[i][0]);
            o.y = f2bf(acc[i][1]);
            o.z = f2bf(acc[i][2]);
            o.w = f2bf(acc[i][3]);
            *(ushort4*)(y + (size_t)(n0 + i) * U + l * 4) = o;
        }
    }

    // ---------------- row scan: one row per wave, branch-free ----------------
    const int wid  = tid >> 6;
    const int lane = tid & 63;
    const int row  = blockIdx.x * 4 + wid;     // 2048*4 == N exactly

    const f32x4* rp = (const f32x4*)(adj + (size_t)row * N);
    u16* crow = cols + (size_t)row * CAP;

    // per-lane 128-bit nonzero bitmap: group g (my g-th float4), bit (g&7)*4+comp
    u32 bm[4] = {0u, 0u, 0u, 0u};

    #pragma unroll
    for (int kb = 0; kb < 4; ++kb) {           // 4 batches of 8 loads
        f32x4 v[8];
        #pragma unroll
        for (int t = 0; t < 8; ++t)            // 8 loads, nothing between them
            v[t] = rp[(kb * 8 + t) * 64 + lane];

        #pragma unroll
        for (int t = 0; t < 8; ++t) {
            const int g = kb * 8 + t;
            // adj values are exactly 0.0f or 1.0f: bit 23 of the encoding.
            const u32 b0 = (__float_as_uint(v[t][0]) >> 23) & 1u;
            const u32 b1 = (__float_as_uint(v[t][1]) >> 22) & 2u;
            const u32 b2 = (__float_as_uint(v[t][2]) >> 21) & 4u;
            const u32 b3 = (__float_as_uint(v[t][3]) >> 20) & 8u;
            bm[g >> 3] |= (b0 | b1 | b2 | b3) << ((g & 7) * 4);
        }
    }

    // counts + exclusive prefix across lanes (order within row is irrelevant)
    const u64 lo = ((u64)bm[1] << 32) | bm[0];   // groups 0..15
    const u64 hi = ((u64)bm[3] << 32) | bm[2];   // groups 16..31
    const int mycnt = __popcll(lo) + __popcll(hi);

    int inc = mycnt;
    #pragma unroll
    for (int off = 1; off < 64; off <<= 1) {
        const int t = __shfl_up(inc, off);
        if (lane >= off) inc += t;
    }
    const int total = __shfl(inc, 63);           // row sum (== nnz, binary adj)
    int pos = inc - mycnt;                       // exclusive prefix

    // extract this lane's set bits (~0.5 avg) -> compacted u16 cols
    u64 b = lo;
    int gbase = 0;
    #pragma unroll
    for (int h = 0; h < 2; ++h) {
        while (b) {
            const int p = __ffsll((unsigned long long)b) - 1;
            b &= b - 1;
            const int g   = gbase + (p >> 2);            // which of my float4s
            const int col = g * 256 + lane * 4 + (p & 3);
            if (pos < CAP) crow[pos] = (u16)col;
            ++pos;
        }
        b = hi;
        gbase = 16;
    }

    if (lane == 0) {
        dinv[row] = 1.0f / sqrtf((float)total + 1.0f);   // +1: self-loop from A+I
        cnt[row]  = min(total, CAP);
    }
}

// ---------------------------------------------------------------------------
// Kernel 2: out[i] = relu(d_i*(d_i*y[i] + sum_j d_j*y[j]) + b).
// One wave per node, zero LDS, full occupancy. 8-neighbor batches:
// 1 uint4 load = 8 packed u16 indices -> 8 parallel dinv gathers ->
// 8 parallel y-row gathers (bf16x2/lane). Bias + ReLU fused at the store.
// ---------------------------------------------------------------------------
__global__ __launch_bounds__(256, 4) void k_agg(const u16* __restrict__ y,
                                                const float* __restrict__ bias,
                                                const float* __restrict__ dinv,
                                                const int* __restrict__ cnt,
                                                const u16* __restrict__ cols,
                                                float* __restrict__ out) {
    const int wid  = threadIdx.x >> 6;
    const int lane = threadIdx.x & 63;
    const int node = blockIdx.x * 4 + wid;

    const int   c  = cnt[node];
    const float di = dinv[node];
    const u16* crow = cols + (size_t)node * CAP;

    const u32 self = *(const u32*)(y + (size_t)node * F + lane * 2);
    float acc0 = di * bflo(self);
    float acc1 = di * bfhi(self);

    for (int m0 = 0; m0 < c; m0 += 8) {
        const uint4 cw = *(const uint4*)(crow + m0);   // 8 u16 indices, 16B aligned
        const u32 cwa[4] = {cw.x, cw.y, cw.z, cw.w};
        int   jj[8];
        float dj[8];
        #pragma unroll
        for (int k = 0; k < 8; ++k) {
            const int  jraw  = (int)((cwa[k >> 1] >> ((k & 1) * 16)) & 0xffffu);
            const bool valid = (m0 + k) < c;
            jj[k] = valid ? jraw : node;               // safe pad address
            dj[k] = valid ? dinv[jj[k]] : 0.f;         // weight 0 kills pad term
        }
        #pragma unroll
        for (int k = 0; k < 8; ++k) {
            const u32 v = *(const u32*)(y + (size_t)jj[k] * F + lane * 2);
            acc0 = fmaf(dj[k], bflo(v), acc0);
            acc1 = fmaf(dj[k], bfhi(v), acc1);
        }
    }

    const float2 bb = *(const float2*)(bias + lane * 2);
    const float o0 = fmaxf(fmaf(di, acc0, bb.x), 0.f);
    const float o1 = fmaxf(fmaf(di, acc1, bb.y), 0.f);
    *(float2*)(out + (size_t)node * F + lane * 2) = make_float2(o0, o1);
}

extern "C" void kernel_launch(void* const* d_in, const int* in_sizes, int n_in,
                              void* d_out, int out_size, void* d_ws, size_t ws_size,
                              hipStream_t stream) {
    const float* x   = (const float*)d_in[0];   // [N, F]
    const float* adj = (const float*)d_in[1];   // [N, N]
    const float* W   = (const float*)d_in[2];   // [F, U]
    const float* b   = (const float*)d_in[3];   // [U]
    float* out = (float*)d_out;                 // [N, U]

    // workspace: dinv f32[N] 32KB | cnt i32[N] 32KB | cols u16[N*CAP] 2MB |
    //            y bf16[N*U] 2MB -> ~4.26MB
    float* dinv = (float*)d_ws;
    int*   cnt  = (int*)((char*)d_ws + (size_t)N * 4);
    u16*   cols = (u16*)((char*)d_ws + (size_t)N * 8);
    u16*   yy   = (u16*)((char*)d_ws + (size_t)N * 8 + (size_t)N * CAP * 2);

    k_fused<<<GRID_BLKS, 256, 0, stream>>>(adj, x, W, dinv, cnt, cols, yy);
    k_agg  <<<N / 4,     256, 0, stream>>>(yy, b, dinv, cnt, cols, out);
}